// Round 1
// baseline (209.860 us; speedup 1.0000x reference)
//
#include <hip/hip_runtime.h>
#include <hip/hip_bf16.h>

typedef short bf16x8 __attribute__((ext_vector_type(8)));
typedef float f32x4 __attribute__((ext_vector_type(4)));
typedef unsigned short u16;

__device__ __forceinline__ u16 f2b(float f) {
  __hip_bfloat16 h = __float2bfloat16(f);
  return *reinterpret_cast<u16*>(&h);
}

#define MFMA16(a, b, c) __builtin_amdgcn_mfma_f32_16x16x32_bf16((a), (b), (c), 0, 0, 0)

// B=2 S=2048 D=1024 H=16 DC=64 HC=16 HD=64

// ---------- fp32 -> bf16 elementwise (n multiple of 1024) ----------
__global__ void k_cvt(const float* __restrict__ in, u16* __restrict__ out, int n) {
  int i = (blockIdx.x * 256 + threadIdx.x) * 4;
  if (i >= n) return;
  float4 v = *reinterpret_cast<const float4*>(in + i);
  ushort4 o;
  o.x = f2b(v.x); o.y = f2b(v.y); o.z = f2b(v.z); o.w = f2b(v.w);
  *reinterpret_cast<ushort4*>(out + i) = o;
}

// ---------- transpose + convert 1024x1024 fp32 weight -> bf16 W^T ----------
__global__ void k_wT(const float* __restrict__ W, u16* __restrict__ WT) {
  __shared__ float t[64][65];
  int tid = threadIdx.x;
  int r0 = (blockIdx.x & 15) << 6;   // k-tile
  int c0 = (blockIdx.x >> 4) << 6;   // n-tile
#pragma unroll
  for (int rep = 0; rep < 4; ++rep) {
    int e = tid + rep * 256;
    int r = e >> 4, c4 = (e & 15) << 2;
    float4 v = *reinterpret_cast<const float4*>(W + (size_t)(r0 + r) * 1024 + c0 + c4);
    t[r][c4] = v.x; t[r][c4 + 1] = v.y; t[r][c4 + 2] = v.z; t[r][c4 + 3] = v.w;
  }
  __syncthreads();
#pragma unroll
  for (int rep = 0; rep < 4; ++rep) {
    int e = tid + rep * 256;
    int c = e >> 4, r4 = (e & 15) << 2;
    ushort4 o;
    o.x = f2b(t[r4][c]); o.y = f2b(t[r4 + 1][c]);
    o.z = f2b(t[r4 + 2][c]); o.w = f2b(t[r4 + 3][c]);
    *reinterpret_cast<ushort4*>(WT + (size_t)(c0 + c) * 1024 + r0 + r4) = o;
  }
}

// ---------- z = coords @ Wc + bc ; Z bf16 [BH][S][16], zsq fp32 [BH][S] ----------
__global__ void k_z(const float* __restrict__ C, const float* __restrict__ Wc,
                    const float* __restrict__ bc, u16* __restrict__ Z,
                    float* __restrict__ zsq) {
  int gid = blockIdx.x * 256 + threadIdx.x;  // 65536 = (B*S)*H
  int bs = gid >> 4, h = gid & 15;
  const float* crow = C + (size_t)bs * 64;
  float acc[16];
#pragma unroll
  for (int c = 0; c < 16; ++c) acc[c] = bc[h * 16 + c];
  for (int k = 0; k < 64; ++k) {
    float cv = crow[k];
    const float* wr = Wc + (size_t)k * 256 + h * 16;
#pragma unroll
    for (int c = 0; c < 16; ++c) acc[c] = fmaf(cv, wr[c], acc[c]);
  }
  float sq = 0.f;
  u16 tmp[16];
#pragma unroll
  for (int c = 0; c < 16; ++c) { sq += acc[c] * acc[c]; tmp[c] = f2b(acc[c]); }
  int b = bs >> 11, s = bs & 2047;
  int bh = (b << 4) + h;
  u16* zr = Z + (((size_t)bh << 11) + s) * 16;
  *reinterpret_cast<uint4*>(zr) = *reinterpret_cast<uint4*>(tmp);
  *reinterpret_cast<uint4*>(zr + 8) = *reinterpret_cast<uint4*>(tmp + 8);
  zsq[((size_t)bh << 11) + s] = sq;
}

// ---------- GEMM C = A(bf16 MxK) * B(bf16, given as B^T NxK) + bias ----------
// OUTM 0: fp32 natural [M][N]; OUTM 1: bf16 scattered to V layout [B,H,S,HD]
template <int OUTM>
__global__ __launch_bounds__(256) void k_gemm(const u16* __restrict__ A,
                                              const u16* __restrict__ BT,
                                              const float* __restrict__ bias,
                                              void* __restrict__ Cout,
                                              int M, int N, int K) {
  __shared__ u16 As[128][40];
  __shared__ u16 Bs[64][40];
  int nbn = N >> 6;
  int bm = blockIdx.x / nbn, bn = blockIdx.x % nbn;
  int tid = threadIdx.x, lane = tid & 63, w = tid >> 6;
  int wm = w >> 1, wn = w & 1;
  int l15 = lane & 15, lg = lane >> 4;
  f32x4 zero = {0.f, 0.f, 0.f, 0.f};
  f32x4 acc[4][2];
#pragma unroll
  for (int mi = 0; mi < 4; ++mi)
#pragma unroll
    for (int ni = 0; ni < 2; ++ni) acc[mi][ni] = zero;

  int ar = tid >> 2, aq = (tid & 3) << 3;
  const u16* Abase = A + (size_t)(bm * 128) * K;
  const u16* Bbase = BT + (size_t)(bn * 64) * K;

  for (int kk = 0; kk < K; kk += 32) {
    __syncthreads();
    *reinterpret_cast<uint4*>(&As[ar][aq]) =
        *reinterpret_cast<const uint4*>(Abase + (size_t)ar * K + kk + aq);
    *reinterpret_cast<uint4*>(&As[ar + 64][aq]) =
        *reinterpret_cast<const uint4*>(Abase + (size_t)(ar + 64) * K + kk + aq);
    *reinterpret_cast<uint4*>(&Bs[ar][aq]) =
        *reinterpret_cast<const uint4*>(Bbase + (size_t)ar * K + kk + aq);
    __syncthreads();
    bf16x8 af[4], bfr[2];
#pragma unroll
    for (int mi = 0; mi < 4; ++mi)
      af[mi] = *reinterpret_cast<const bf16x8*>(&As[wm * 64 + mi * 16 + l15][lg * 8]);
#pragma unroll
    for (int ni = 0; ni < 2; ++ni)
      bfr[ni] = *reinterpret_cast<const bf16x8*>(&Bs[wn * 32 + ni * 16 + l15][lg * 8]);
#pragma unroll
    for (int mi = 0; mi < 4; ++mi)
#pragma unroll
      for (int ni = 0; ni < 2; ++ni)
        acc[mi][ni] = MFMA16(af[mi], bfr[ni], acc[mi][ni]);
  }
#pragma unroll
  for (int mi = 0; mi < 4; ++mi) {
#pragma unroll
    for (int ni = 0; ni < 2; ++ni) {
      int col = bn * 64 + wn * 32 + ni * 16 + l15;
      float bb = bias[col];
#pragma unroll
      for (int j = 0; j < 4; ++j) {
        int row = bm * 128 + wm * 64 + mi * 16 + lg * 4 + j;
        float v = acc[mi][ni][j] + bb;
        if (OUTM == 0) {
          reinterpret_cast<float*>(Cout)[(size_t)row * N + col] = v;
        } else {
          int b = row >> 11, s = row & 2047, h = col >> 6, hd = col & 63;
          reinterpret_cast<u16*>(Cout)[((((size_t)(b * 16 + h) << 11) | s) << 6) + hd] = f2b(v);
        }
      }
    }
  }
}

// ---------- V [BH][S][64] -> VT [BH][64][S]  (bf16) ----------
__global__ void k_vT(const u16* __restrict__ V, u16* __restrict__ VT) {
  __shared__ u16 t[64][72];
  int tid = threadIdx.x;
  int bh = blockIdx.x >> 5;
  int s0 = (blockIdx.x & 31) << 6;
#pragma unroll
  for (int rep = 0; rep < 2; ++rep) {
    int e = tid + rep * 256;
    int sl = e >> 3, seg = (e & 7) << 3;
    *reinterpret_cast<uint4*>(&t[sl][seg]) =
        *reinterpret_cast<const uint4*>(V + ((size_t)(bh * 2048 + s0 + sl) << 6) + seg);
  }
  __syncthreads();
#pragma unroll
  for (int rep = 0; rep < 2; ++rep) {
    int e = tid + rep * 256;
    int hd = e >> 3, ss = (e & 7) << 3;
    u16 tmp[8];
#pragma unroll
    for (int i = 0; i < 8; ++i) tmp[i] = t[ss + i][hd];
    *reinterpret_cast<uint4*>(VT + ((size_t)(bh * 64 + hd) << 11) + s0 + ss) =
        *reinterpret_cast<uint4*>(tmp);
  }
}

// ---------- flash attention over gravity scores ----------
__global__ __launch_bounds__(256) void k_attn(const u16* __restrict__ Z,
                                              const float* __restrict__ zsq,
                                              const u16* __restrict__ VT,
                                              const float* __restrict__ gamma,
                                              u16* __restrict__ O) {
  __shared__ u16 Zq[64][40];
  __shared__ u16 Zt[64][40];
  __shared__ u16 Vt[64][72];
  __shared__ u16 P[64][72];
  __shared__ float tsq[64];

  int tid = threadIdx.x, lane = tid & 63, w = tid >> 6;
  int l15 = lane & 15, lg = lane >> 4;
  int bh = blockIdx.x >> 5, qt = blockIdx.x & 31;
  int q0 = qt << 6;
  int h = bh & 15, b = bh >> 4;
  float gm = gamma[h];
  float g = (gm > 15.f) ? gm : log1pf(__expf(gm));  // softplus

  const u16* Zb = Z + ((size_t)bh << 11) * 16;
  const float* zsb = zsq + ((size_t)bh << 11);
  const u16* Vb = VT + ((size_t)bh << 6) * 2048;

  {
    int r = tid >> 2, c4 = (tid & 3) << 2;
    *reinterpret_cast<uint2*>(&Zq[r][c4]) =
        *reinterpret_cast<const uint2*>(Zb + (size_t)(q0 + r) * 16 + c4);
    *reinterpret_cast<uint2*>(&Zq[r][16 + c4]) = make_uint2(0u, 0u);  // K pad
    *reinterpret_cast<uint2*>(&Zt[r][16 + c4]) = make_uint2(0u, 0u);  // K pad (persistent)
  }
  float zq[4], mrow[4], lsum[4];
#pragma unroll
  for (int j = 0; j < 4; ++j) {
    zq[j] = zsb[q0 + w * 16 + lg * 4 + j];
    mrow[j] = -3.0e38f;
    lsum[j] = 0.f;
  }
  f32x4 zero = {0.f, 0.f, 0.f, 0.f};
  f32x4 oacc[4];
#pragma unroll
  for (int ni = 0; ni < 4; ++ni) oacc[ni] = zero;
  __syncthreads();
  bf16x8 aqf = *reinterpret_cast<const bf16x8*>(&Zq[w * 16 + l15][lg * 8]);

  for (int tt = 0; tt < 32; ++tt) {
    int t0 = tt << 6;
    if (tt) __syncthreads();
    {
      int r = tid >> 2, c4 = (tid & 3) << 2;
      *reinterpret_cast<uint2*>(&Zt[r][c4]) =
          *reinterpret_cast<const uint2*>(Zb + (size_t)(t0 + r) * 16 + c4);
    }
    if (tid < 64) tsq[tid] = zsb[t0 + tid];
#pragma unroll
    for (int rep = 0; rep < 2; ++rep) {
      int e = tid + rep * 256;
      int hd = e >> 3, seg = (e & 7) << 3;
      *reinterpret_cast<uint4*>(&Vt[hd][seg]) =
          *reinterpret_cast<const uint4*>(Vb + ((size_t)hd << 11) + t0 + seg);
    }
    __syncthreads();

    // scores: dot(q,t) via MFMA, then s = -g*max(zsq_q + zsq_t - 2 dot, 0)
    f32x4 sc[4];
#pragma unroll
    for (int ni = 0; ni < 4; ++ni) {
      bf16x8 bt = *reinterpret_cast<const bf16x8*>(&Zt[ni * 16 + l15][lg * 8]);
      sc[ni] = MFMA16(aqf, bt, zero);
    }
    float tq[4];
#pragma unroll
    for (int ni = 0; ni < 4; ++ni) tq[ni] = tsq[ni * 16 + l15];
    float tmax[4] = {-3.0e38f, -3.0e38f, -3.0e38f, -3.0e38f};
#pragma unroll
    for (int ni = 0; ni < 4; ++ni)
#pragma unroll
      for (int j = 0; j < 4; ++j) {
        float d = zq[j] + tq[ni] - 2.f * sc[ni][j];
        d = fmaxf(d, 0.f);
        float s = -g * d;
        sc[ni][j] = s;
        tmax[j] = fmaxf(tmax[j], s);
      }
#pragma unroll
    for (int m = 1; m <= 8; m <<= 1)
#pragma unroll
      for (int j = 0; j < 4; ++j)
        tmax[j] = fmaxf(tmax[j], __shfl_xor(tmax[j], m, 64));
    float psum[4];
#pragma unroll
    for (int j = 0; j < 4; ++j) {
      float mn = fmaxf(mrow[j], tmax[j]);
      float rs = __expf(mrow[j] - mn);
      mrow[j] = mn;
      lsum[j] *= rs;
#pragma unroll
      for (int ni = 0; ni < 4; ++ni) oacc[ni][j] *= rs;
      psum[j] = 0.f;
    }
#pragma unroll
    for (int ni = 0; ni < 4; ++ni)
#pragma unroll
      for (int j = 0; j < 4; ++j) {
        float p = __expf(sc[ni][j] - mrow[j]);
        psum[j] += p;
        P[w * 16 + lg * 4 + j][ni * 16 + l15] = f2b(p);
      }
#pragma unroll
    for (int m = 1; m <= 8; m <<= 1)
#pragma unroll
      for (int j = 0; j < 4; ++j) psum[j] += __shfl_xor(psum[j], m, 64);
#pragma unroll
    for (int j = 0; j < 4; ++j) lsum[j] += psum[j];

    // PV: oacc += P * Vt   (same-wave P write->read, ordered by lgkmcnt)
#pragma unroll
    for (int ks = 0; ks < 2; ++ks) {
      bf16x8 pa = *reinterpret_cast<const bf16x8*>(&P[w * 16 + l15][ks * 32 + lg * 8]);
#pragma unroll
      for (int ni = 0; ni < 4; ++ni) {
        bf16x8 vb = *reinterpret_cast<const bf16x8*>(&Vt[ni * 16 + l15][ks * 32 + lg * 8]);
        oacc[ni] = MFMA16(pa, vb, oacc[ni]);
      }
    }
  }
#pragma unroll
  for (int j = 0; j < 4; ++j) {
    float inv = 1.f / lsum[j];
    int s = q0 + w * 16 + lg * 4 + j;
    u16* orow = O + ((size_t)(b * 2048 + s) << 10) + h * 64;
#pragma unroll
    for (int ni = 0; ni < 4; ++ni) orow[ni * 16 + l15] = f2b(oacc[ni][j] * inv);
  }
}

// ---------- updated_coords = coords @ Wn + bn (fp32) ----------
__global__ void k_coords(const float* __restrict__ C, const float* __restrict__ Wn,
                         const float* __restrict__ bn, float* __restrict__ out) {
  int gid = blockIdx.x * 256 + threadIdx.x;  // 262144
  int bs = gid >> 6, c = gid & 63;
  const float* crow = C + (size_t)bs * 64;
  float acc = bn[c];
#pragma unroll 8
  for (int k = 0; k < 64; ++k) acc = fmaf(crow[k], Wn[k * 64 + c], acc);
  out[gid] = acc;
}

extern "C" void kernel_launch(void* const* d_in, const int* in_sizes, int n_in,
                              void* d_out, int out_size, void* d_ws, size_t ws_size,
                              hipStream_t stream) {
  const float* hs     = (const float*)d_in[0];
  const float* coords = (const float*)d_in[1];
  const float* Wv     = (const float*)d_in[2];
  const float* bv     = (const float*)d_in[3];
  const float* Wc     = (const float*)d_in[4];
  const float* bc     = (const float*)d_in[5];
  const float* Wn     = (const float*)d_in[6];
  const float* bn     = (const float*)d_in[7];
  const float* Wo     = (const float*)d_in[8];
  const float* bo     = (const float*)d_in[9];
  const float* gamma  = (const float*)d_in[10];
  float* out_h = (float*)d_out;
  float* out_c = out_h + 4194304;

  char* ws = (char*)d_ws;
  u16*   HSb  = (u16*)(ws + 0);          // 8 MB   (reused as O after gemm1)
  u16*   O    = (u16*)(ws + 0);
  u16*   WvT  = (u16*)(ws + 8388608);    // 2 MB
  u16*   WoT  = (u16*)(ws + 10485760);   // 2 MB
  u16*   Zw   = (u16*)(ws + 12582912);   // 2 MB
  float* zsqw = (float*)(ws + 14680064); // 0.25 MB
  u16*   Vw   = (u16*)(ws + 14942208);   // 8 MB
  u16*   VTw  = (u16*)(ws + 23330816);   // 8 MB  -> total 31.7 MB

  k_cvt<<<4096, 256, 0, stream>>>(hs, HSb, 4194304);
  k_wT<<<256, 256, 0, stream>>>(Wv, WvT);
  k_wT<<<256, 256, 0, stream>>>(Wo, WoT);
  k_z<<<256, 256, 0, stream>>>(coords, Wc, bc, Zw, zsqw);
  k_gemm<1><<<512, 256, 0, stream>>>(HSb, WvT, bv, Vw, 4096, 1024, 1024);
  k_vT<<<1024, 256, 0, stream>>>(Vw, VTw);
  k_attn<<<1024, 256, 0, stream>>>(Zw, zsqw, VTw, gamma, O);
  k_gemm<0><<<512, 256, 0, stream>>>(O, WoT, bo, out_h, 4096, 1024, 1024);
  k_coords<<<1024, 256, 0, stream>>>(coords, Wn, bn, out_c);
}

// Round 2
// 173.964 us; speedup vs baseline: 1.2063x; 1.2063x over previous
//
#include <hip/hip_runtime.h>
#include <hip/hip_bf16.h>

typedef short bf16x8 __attribute__((ext_vector_type(8)));
typedef float f32x4 __attribute__((ext_vector_type(4)));
typedef unsigned short u16;

__device__ __forceinline__ u16 f2b(float f) {
  __hip_bfloat16 h = __float2bfloat16(f);
  return *reinterpret_cast<u16*>(&h);
}

#define MFMA16(a, b, c) __builtin_amdgcn_mfma_f32_16x16x32_bf16((a), (b), (c), 0, 0, 0)

// B=2 S=2048 D=1024 H=16 DC=64 HC=16 HD=64

// ---------- fp32 -> bf16 elementwise (n multiple of 1024) ----------
__global__ void k_cvt(const float* __restrict__ in, u16* __restrict__ out, int n) {
  int i = (blockIdx.x * 256 + threadIdx.x) * 4;
  if (i >= n) return;
  float4 v = *reinterpret_cast<const float4*>(in + i);
  ushort4 o;
  o.x = f2b(v.x); o.y = f2b(v.y); o.z = f2b(v.z); o.w = f2b(v.w);
  *reinterpret_cast<ushort4*>(out + i) = o;
}

// ---------- transpose + convert 1024x1024 fp32 weight -> bf16 W^T ----------
__global__ void k_wT(const float* __restrict__ W, u16* __restrict__ WT) {
  __shared__ float t[64][65];
  int tid = threadIdx.x;
  int r0 = (blockIdx.x & 15) << 6;   // k-tile
  int c0 = (blockIdx.x >> 4) << 6;   // n-tile
#pragma unroll
  for (int rep = 0; rep < 4; ++rep) {
    int e = tid + rep * 256;
    int r = e >> 4, c4 = (e & 15) << 2;
    float4 v = *reinterpret_cast<const float4*>(W + (size_t)(r0 + r) * 1024 + c0 + c4);
    t[r][c4] = v.x; t[r][c4 + 1] = v.y; t[r][c4 + 2] = v.z; t[r][c4 + 3] = v.w;
  }
  __syncthreads();
#pragma unroll
  for (int rep = 0; rep < 4; ++rep) {
    int e = tid + rep * 256;
    int c = e >> 4, r4 = (e & 15) << 2;
    ushort4 o;
    o.x = f2b(t[r4][c]); o.y = f2b(t[r4 + 1][c]);
    o.z = f2b(t[r4 + 2][c]); o.w = f2b(t[r4 + 3][c]);
    *reinterpret_cast<ushort4*>(WT + (size_t)(c0 + c) * 1024 + r0 + r4) = o;
  }
}

// ---------- z = coords @ Wc + bc ; Z bf16 [BH][S][16], zsq fp32 [BH][S] ----------
__global__ void k_z(const float* __restrict__ C, const float* __restrict__ Wc,
                    const float* __restrict__ bc, u16* __restrict__ Z,
                    float* __restrict__ zsq) {
  int gid = blockIdx.x * 256 + threadIdx.x;  // 65536 = (B*S)*H
  int bs = gid >> 4, h = gid & 15;
  const float* crow = C + (size_t)bs * 64;
  float acc[16];
#pragma unroll
  for (int c = 0; c < 16; ++c) acc[c] = bc[h * 16 + c];
  for (int k = 0; k < 64; ++k) {
    float cv = crow[k];
    const float* wr = Wc + (size_t)k * 256 + h * 16;
#pragma unroll
    for (int c = 0; c < 16; ++c) acc[c] = fmaf(cv, wr[c], acc[c]);
  }
  float sq = 0.f;
  u16 tmp[16];
#pragma unroll
  for (int c = 0; c < 16; ++c) { sq += acc[c] * acc[c]; tmp[c] = f2b(acc[c]); }
  int b = bs >> 11, s = bs & 2047;
  int bh = (b << 4) + h;
  u16* zr = Z + (((size_t)bh << 11) + s) * 16;
  *reinterpret_cast<uint4*>(zr) = *reinterpret_cast<uint4*>(tmp);
  *reinterpret_cast<uint4*>(zr + 8) = *reinterpret_cast<uint4*>(tmp + 8);
  zsq[((size_t)bh << 11) + s] = sq;
}

// ---------- GEMM C = A(bf16 MxK) * B(bf16, given as B^T NxK) + bias ----------
// OUTM 0: fp32 natural [M][N]; OUTM 1: bf16 scattered to V layout [B,H,S,HD]
template <int OUTM>
__global__ __launch_bounds__(256) void k_gemm(const u16* __restrict__ A,
                                              const u16* __restrict__ BT,
                                              const float* __restrict__ bias,
                                              void* __restrict__ Cout,
                                              int M, int N, int K) {
  __shared__ u16 As[128][40];
  __shared__ u16 Bs[64][40];
  int nbn = N >> 6;
  int bm = blockIdx.x / nbn, bn = blockIdx.x % nbn;
  int tid = threadIdx.x, lane = tid & 63, w = tid >> 6;
  int wm = w >> 1, wn = w & 1;
  int l15 = lane & 15, lg = lane >> 4;
  f32x4 zero = {0.f, 0.f, 0.f, 0.f};
  f32x4 acc[4][2];
#pragma unroll
  for (int mi = 0; mi < 4; ++mi)
#pragma unroll
    for (int ni = 0; ni < 2; ++ni) acc[mi][ni] = zero;

  int ar = tid >> 2, aq = (tid & 3) << 3;
  const u16* Abase = A + (size_t)(bm * 128) * K;
  const u16* Bbase = BT + (size_t)(bn * 64) * K;

  for (int kk = 0; kk < K; kk += 32) {
    __syncthreads();
    *reinterpret_cast<uint4*>(&As[ar][aq]) =
        *reinterpret_cast<const uint4*>(Abase + (size_t)ar * K + kk + aq);
    *reinterpret_cast<uint4*>(&As[ar + 64][aq]) =
        *reinterpret_cast<const uint4*>(Abase + (size_t)(ar + 64) * K + kk + aq);
    *reinterpret_cast<uint4*>(&Bs[ar][aq]) =
        *reinterpret_cast<const uint4*>(Bbase + (size_t)ar * K + kk + aq);
    __syncthreads();
    bf16x8 af[4], bfr[2];
#pragma unroll
    for (int mi = 0; mi < 4; ++mi)
      af[mi] = *reinterpret_cast<const bf16x8*>(&As[wm * 64 + mi * 16 + l15][lg * 8]);
#pragma unroll
    for (int ni = 0; ni < 2; ++ni)
      bfr[ni] = *reinterpret_cast<const bf16x8*>(&Bs[wn * 32 + ni * 16 + l15][lg * 8]);
#pragma unroll
    for (int mi = 0; mi < 4; ++mi)
#pragma unroll
      for (int ni = 0; ni < 2; ++ni)
        acc[mi][ni] = MFMA16(af[mi], bfr[ni], acc[mi][ni]);
  }
#pragma unroll
  for (int mi = 0; mi < 4; ++mi) {
#pragma unroll
    for (int ni = 0; ni < 2; ++ni) {
      int col = bn * 64 + wn * 32 + ni * 16 + l15;
      float bb = bias[col];
#pragma unroll
      for (int j = 0; j < 4; ++j) {
        int row = bm * 128 + wm * 64 + mi * 16 + lg * 4 + j;
        float v = acc[mi][ni][j] + bb;
        if (OUTM == 0) {
          reinterpret_cast<float*>(Cout)[(size_t)row * N + col] = v;
        } else {
          int b = row >> 11, s = row & 2047, h = col >> 6, hd = col & 63;
          reinterpret_cast<u16*>(Cout)[((((size_t)(b * 16 + h) << 11) | s) << 6) + hd] = f2b(v);
        }
      }
    }
  }
}

// ---------- V [BH][S][64] -> VT [BH][64][S]  (bf16) ----------
__global__ void k_vT(const u16* __restrict__ V, u16* __restrict__ VT) {
  __shared__ u16 t[64][72];
  int tid = threadIdx.x;
  int bh = blockIdx.x >> 5;
  int s0 = (blockIdx.x & 31) << 6;
#pragma unroll
  for (int rep = 0; rep < 2; ++rep) {
    int e = tid + rep * 256;
    int sl = e >> 3, seg = (e & 7) << 3;
    *reinterpret_cast<uint4*>(&t[sl][seg]) =
        *reinterpret_cast<const uint4*>(V + ((size_t)(bh * 2048 + s0 + sl) << 6) + seg);
  }
  __syncthreads();
#pragma unroll
  for (int rep = 0; rep < 2; ++rep) {
    int e = tid + rep * 256;
    int hd = e >> 3, ss = (e & 7) << 3;
    u16 tmp[8];
#pragma unroll
    for (int i = 0; i < 8; ++i) tmp[i] = t[ss + i][hd];
    *reinterpret_cast<uint4*>(VT + ((size_t)(bh * 64 + hd) << 11) + s0 + ss) =
        *reinterpret_cast<uint4*>(tmp);
  }
}

// ---------- flash attention over gravity scores ----------
// Scores are always <= 0 with row-max exactly 0 (diagonal: sq_dist==0), so no
// online max tracking / rescaling is needed. p = exp2(min(2*g2*dot - g2*(zq+tq), 0)).
__global__ __launch_bounds__(256) void k_attn(const u16* __restrict__ Z,
                                              const float* __restrict__ zsq,
                                              const u16* __restrict__ VT,
                                              const float* __restrict__ gamma,
                                              u16* __restrict__ O) {
  __shared__ u16 Zt[64][40];
  __shared__ u16 Vt[64][72];
  __shared__ u16 P[64][76];
  __shared__ float tsq[64];

  int tid = threadIdx.x, lane = tid & 63, w = tid >> 6;
  int l15 = lane & 15, lg = lane >> 4;
  int bh = blockIdx.x >> 5, qt = blockIdx.x & 31;
  int q0 = qt << 6;
  int h = bh & 15, b = bh >> 4;
  float gm = gamma[h];
  float g = (gm > 15.f) ? gm : log1pf(__expf(gm));  // softplus
  float g2 = g * 1.4426950408889634f;               // fold log2(e) -> use exp2
  float tg2 = 2.f * g2;

  const u16* Zb = Z + ((size_t)bh << 11) * 16;
  const float* zsb = zsq + ((size_t)bh << 11);
  const u16* Vb = VT + ((size_t)bh << 6) * 2048;

  {  // persistent zero K-pad of Zt (cols 16..31)
    int r = tid >> 2, c4 = (tid & 3) << 2;
    *reinterpret_cast<uint2*>(&Zt[r][16 + c4]) = make_uint2(0u, 0u);
  }
  // A-fragment of Q directly from global (k = lg*8 + 0..7; zero for k>=16)
  bf16x8 aqf = {};
  if (lg < 2)
    aqf = *reinterpret_cast<const bf16x8*>(Zb + (size_t)(q0 + w * 16 + l15) * 16 + lg * 8);

  float gzq[4], psum[4];
#pragma unroll
  for (int j = 0; j < 4; ++j) {
    gzq[j] = -g2 * zsb[q0 + w * 16 + lg * 4 + j];
    psum[j] = 0.f;
  }
  f32x4 zero = {0.f, 0.f, 0.f, 0.f};
  f32x4 oacc[4];
#pragma unroll
  for (int ni = 0; ni < 4; ++ni) oacc[ni] = zero;

  for (int tt = 0; tt < 32; ++tt) {
    int t0 = tt << 6;
    if (tt) __syncthreads();
    {
      int r = tid >> 2, c4 = (tid & 3) << 2;
      *reinterpret_cast<uint2*>(&Zt[r][c4]) =
          *reinterpret_cast<const uint2*>(Zb + (size_t)(t0 + r) * 16 + c4);
    }
    if (tid < 64) tsq[tid] = zsb[t0 + tid];
#pragma unroll
    for (int rep = 0; rep < 2; ++rep) {
      int e = tid + rep * 256;
      int hd = e >> 3, seg = (e & 7) << 3;
      *reinterpret_cast<uint4*>(&Vt[hd][seg]) =
          *reinterpret_cast<const uint4*>(Vb + ((size_t)hd << 11) + t0 + seg);
    }
    __syncthreads();

    // scores via MFMA dot, then p = exp2(min(tg2*dot + (gzq+gtq), 0))
    f32x4 sc[4];
    float gtq[4];
#pragma unroll
    for (int ni = 0; ni < 4; ++ni) {
      bf16x8 bt = *reinterpret_cast<const bf16x8*>(&Zt[ni * 16 + l15][lg * 8]);
      sc[ni] = MFMA16(aqf, bt, zero);
      gtq[ni] = -g2 * tsq[ni * 16 + l15];
    }
#pragma unroll
    for (int ni = 0; ni < 4; ++ni) {
      float qtg0 = gtq[ni];
#pragma unroll
      for (int j = 0; j < 4; ++j) {
        float e = fmaf(tg2, sc[ni][j], gzq[j] + qtg0);
        e = fminf(e, 0.f);
        float p = exp2f(e);
        psum[j] += p;
        P[w * 16 + lg * 4 + j][ni * 16 + l15] = f2b(p);
      }
    }

    // PV: oacc += P * Vt   (same-wave P write->read, ordered by LDS pipeline)
#pragma unroll
    for (int ks = 0; ks < 2; ++ks) {
      bf16x8 pa = *reinterpret_cast<const bf16x8*>(&P[w * 16 + l15][ks * 32 + lg * 8]);
#pragma unroll
      for (int ni = 0; ni < 4; ++ni) {
        bf16x8 vb = *reinterpret_cast<const bf16x8*>(&Vt[ni * 16 + l15][ks * 32 + lg * 8]);
        oacc[ni] = MFMA16(pa, vb, oacc[ni]);
      }
    }
  }

  // single cross-lane reduction of psum at the end (sum over l15 group)
#pragma unroll
  for (int m = 1; m <= 8; m <<= 1)
#pragma unroll
    for (int j = 0; j < 4; ++j) psum[j] += __shfl_xor(psum[j], m, 64);

#pragma unroll
  for (int j = 0; j < 4; ++j) {
    float inv = 1.f / psum[j];
    int s = q0 + w * 16 + lg * 4 + j;
    u16* orow = O + ((size_t)(b * 2048 + s) << 10) + h * 64;
#pragma unroll
    for (int ni = 0; ni < 4; ++ni) orow[ni * 16 + l15] = f2b(oacc[ni][j] * inv);
  }
}

// ---------- updated_coords = coords @ Wn + bn (fp32) ----------
__global__ void k_coords(const float* __restrict__ C, const float* __restrict__ Wn,
                         const float* __restrict__ bn, float* __restrict__ out) {
  int gid = blockIdx.x * 256 + threadIdx.x;  // 262144
  int bs = gid >> 6, c = gid & 63;
  const float* crow = C + (size_t)bs * 64;
  float acc = bn[c];
#pragma unroll 8
  for (int k = 0; k < 64; ++k) acc = fmaf(crow[k], Wn[k * 64 + c], acc);
  out[gid] = acc;
}

extern "C" void kernel_launch(void* const* d_in, const int* in_sizes, int n_in,
                              void* d_out, int out_size, void* d_ws, size_t ws_size,
                              hipStream_t stream) {
  const float* hs     = (const float*)d_in[0];
  const float* coords = (const float*)d_in[1];
  const float* Wv     = (const float*)d_in[2];
  const float* bv     = (const float*)d_in[3];
  const float* Wc     = (const float*)d_in[4];
  const float* bc     = (const float*)d_in[5];
  const float* Wn     = (const float*)d_in[6];
  const float* bn     = (const float*)d_in[7];
  const float* Wo     = (const float*)d_in[8];
  const float* bo     = (const float*)d_in[9];
  const float* gamma  = (const float*)d_in[10];
  float* out_h = (float*)d_out;
  float* out_c = out_h + 4194304;

  char* ws = (char*)d_ws;
  u16*   HSb  = (u16*)(ws + 0);          // 8 MB   (reused as O after gemm1)
  u16*   O    = (u16*)(ws + 0);
  u16*   WvT  = (u16*)(ws + 8388608);    // 2 MB
  u16*   WoT  = (u16*)(ws + 10485760);   // 2 MB
  u16*   Zw   = (u16*)(ws + 12582912);   // 2 MB
  float* zsqw = (float*)(ws + 14680064); // 0.25 MB
  u16*   Vw   = (u16*)(ws + 14942208);   // 8 MB
  u16*   VTw  = (u16*)(ws + 23330816);   // 8 MB  -> total 31.7 MB

  k_cvt<<<4096, 256, 0, stream>>>(hs, HSb, 4194304);
  k_wT<<<256, 256, 0, stream>>>(Wv, WvT);
  k_wT<<<256, 256, 0, stream>>>(Wo, WoT);
  k_z<<<256, 256, 0, stream>>>(coords, Wc, bc, Zw, zsqw);
  k_gemm<1><<<512, 256, 0, stream>>>(HSb, WvT, bv, Vw, 4096, 1024, 1024);
  k_vT<<<1024, 256, 0, stream>>>(Vw, VTw);
  k_attn<<<1024, 256, 0, stream>>>(Zw, zsqw, VTw, gamma, O);
  k_gemm<0><<<512, 256, 0, stream>>>(O, WoT, bo, out_h, 4096, 1024, 1024);
  k_coords<<<1024, 256, 0, stream>>>(coords, Wn, bn, out_c);
}

// Round 3
// 157.624 us; speedup vs baseline: 1.3314x; 1.1037x over previous
//
#include <hip/hip_runtime.h>
#include <hip/hip_bf16.h>

typedef short bf16x8 __attribute__((ext_vector_type(8)));
typedef float f32x4 __attribute__((ext_vector_type(4)));
typedef unsigned short u16;

__device__ __forceinline__ u16 f2b(float f) {
  __hip_bfloat16 h = __float2bfloat16(f);
  return *reinterpret_cast<u16*>(&h);
}

#define MFMA16(a, b, c) __builtin_amdgcn_mfma_f32_16x16x32_bf16((a), (b), (c), 0, 0, 0)

// B=2 S=2048 D=1024 H=16 DC=64 HC=16 HD=64

// ---------- fp32 -> bf16 elementwise (n multiple of 1024) ----------
__global__ void k_cvt(const float* __restrict__ in, u16* __restrict__ out, int n) {
  int i = (blockIdx.x * 256 + threadIdx.x) * 4;
  if (i >= n) return;
  float4 v = *reinterpret_cast<const float4*>(in + i);
  ushort4 o;
  o.x = f2b(v.x); o.y = f2b(v.y); o.z = f2b(v.z); o.w = f2b(v.w);
  *reinterpret_cast<ushort4*>(out + i) = o;
}

// ---------- transpose + convert 1024x1024 fp32 weight -> bf16 W^T ----------
__global__ void k_wT(const float* __restrict__ W, u16* __restrict__ WT) {
  __shared__ float t[64][65];
  int tid = threadIdx.x;
  int r0 = (blockIdx.x & 15) << 6;   // k-tile
  int c0 = (blockIdx.x >> 4) << 6;   // n-tile
#pragma unroll
  for (int rep = 0; rep < 4; ++rep) {
    int e = tid + rep * 256;
    int r = e >> 4, c4 = (e & 15) << 2;
    float4 v = *reinterpret_cast<const float4*>(W + (size_t)(r0 + r) * 1024 + c0 + c4);
    t[r][c4] = v.x; t[r][c4 + 1] = v.y; t[r][c4 + 2] = v.z; t[r][c4 + 3] = v.w;
  }
  __syncthreads();
#pragma unroll
  for (int rep = 0; rep < 4; ++rep) {
    int e = tid + rep * 256;
    int c = e >> 4, r4 = (e & 15) << 2;
    ushort4 o;
    o.x = f2b(t[r4][c]); o.y = f2b(t[r4 + 1][c]);
    o.z = f2b(t[r4 + 2][c]); o.w = f2b(t[r4 + 3][c]);
    *reinterpret_cast<ushort4*>(WT + (size_t)(c0 + c) * 1024 + r0 + r4) = o;
  }
}

// ---------- z = coords @ Wc + bc ; Z bf16 [BH][S][16], zsq fp32 [BH][S] ----------
__global__ void k_z(const float* __restrict__ C, const float* __restrict__ Wc,
                    const float* __restrict__ bc, u16* __restrict__ Z,
                    float* __restrict__ zsq) {
  int gid = blockIdx.x * 256 + threadIdx.x;  // 65536 = (B*S)*H
  int bs = gid >> 4, h = gid & 15;
  const float* crow = C + (size_t)bs * 64;
  float acc[16];
#pragma unroll
  for (int c = 0; c < 16; ++c) acc[c] = bc[h * 16 + c];
  for (int k = 0; k < 64; ++k) {
    float cv = crow[k];
    const float* wr = Wc + (size_t)k * 256 + h * 16;
#pragma unroll
    for (int c = 0; c < 16; ++c) acc[c] = fmaf(cv, wr[c], acc[c]);
  }
  float sq = 0.f;
  u16 tmp[16];
#pragma unroll
  for (int c = 0; c < 16; ++c) { sq += acc[c] * acc[c]; tmp[c] = f2b(acc[c]); }
  int b = bs >> 11, s = bs & 2047;
  int bh = (b << 4) + h;
  u16* zr = Z + (((size_t)bh << 11) + s) * 16;
  *reinterpret_cast<uint4*>(zr) = *reinterpret_cast<uint4*>(tmp);
  *reinterpret_cast<uint4*>(zr + 8) = *reinterpret_cast<uint4*>(tmp + 8);
  zsq[((size_t)bh << 11) + s] = sq;
}

// ---------- GEMM C = A(bf16 MxK) * B(bf16, given as B^T NxK) + bias ----------
// OUTM 0: fp32 natural [M][N]; OUTM 1: bf16 scattered to V layout [B,H,S,HD]
template <int OUTM>
__global__ __launch_bounds__(256) void k_gemm(const u16* __restrict__ A,
                                              const u16* __restrict__ BT,
                                              const float* __restrict__ bias,
                                              void* __restrict__ Cout,
                                              int M, int N, int K) {
  __shared__ u16 As[128][40];
  __shared__ u16 Bs[64][40];
  int nbn = N >> 6;
  int bm = blockIdx.x / nbn, bn = blockIdx.x % nbn;
  int tid = threadIdx.x, lane = tid & 63, w = tid >> 6;
  int wm = w >> 1, wn = w & 1;
  int l15 = lane & 15, lg = lane >> 4;
  f32x4 zero = {0.f, 0.f, 0.f, 0.f};
  f32x4 acc[4][2];
#pragma unroll
  for (int mi = 0; mi < 4; ++mi)
#pragma unroll
    for (int ni = 0; ni < 2; ++ni) acc[mi][ni] = zero;

  int ar = tid >> 2, aq = (tid & 3) << 3;
  const u16* Abase = A + (size_t)(bm * 128) * K;
  const u16* Bbase = BT + (size_t)(bn * 64) * K;

  for (int kk = 0; kk < K; kk += 32) {
    __syncthreads();
    *reinterpret_cast<uint4*>(&As[ar][aq]) =
        *reinterpret_cast<const uint4*>(Abase + (size_t)ar * K + kk + aq);
    *reinterpret_cast<uint4*>(&As[ar + 64][aq]) =
        *reinterpret_cast<const uint4*>(Abase + (size_t)(ar + 64) * K + kk + aq);
    *reinterpret_cast<uint4*>(&Bs[ar][aq]) =
        *reinterpret_cast<const uint4*>(Bbase + (size_t)ar * K + kk + aq);
    __syncthreads();
    bf16x8 af[4], bfr[2];
#pragma unroll
    for (int mi = 0; mi < 4; ++mi)
      af[mi] = *reinterpret_cast<const bf16x8*>(&As[wm * 64 + mi * 16 + l15][lg * 8]);
#pragma unroll
    for (int ni = 0; ni < 2; ++ni)
      bfr[ni] = *reinterpret_cast<const bf16x8*>(&Bs[wn * 32 + ni * 16 + l15][lg * 8]);
#pragma unroll
    for (int mi = 0; mi < 4; ++mi)
#pragma unroll
      for (int ni = 0; ni < 2; ++ni)
        acc[mi][ni] = MFMA16(af[mi], bfr[ni], acc[mi][ni]);
  }
#pragma unroll
  for (int mi = 0; mi < 4; ++mi) {
#pragma unroll
    for (int ni = 0; ni < 2; ++ni) {
      int col = bn * 64 + wn * 32 + ni * 16 + l15;
      float bb = bias[col];
#pragma unroll
      for (int j = 0; j < 4; ++j) {
        int row = bm * 128 + wm * 64 + mi * 16 + lg * 4 + j;
        float v = acc[mi][ni][j] + bb;
        if (OUTM == 0) {
          reinterpret_cast<float*>(Cout)[(size_t)row * N + col] = v;
        } else {
          int b = row >> 11, s = row & 2047, h = col >> 6, hd = col & 63;
          reinterpret_cast<u16*>(Cout)[((((size_t)(b * 16 + h) << 11) | s) << 6) + hd] = f2b(v);
        }
      }
    }
  }
}

// ---------- V [BH][S][64] -> VT [BH][64][S]  (bf16) ----------
__global__ void k_vT(const u16* __restrict__ V, u16* __restrict__ VT) {
  __shared__ u16 t[64][72];
  int tid = threadIdx.x;
  int bh = blockIdx.x >> 5;
  int s0 = (blockIdx.x & 31) << 6;
#pragma unroll
  for (int rep = 0; rep < 2; ++rep) {
    int e = tid + rep * 256;
    int sl = e >> 3, seg = (e & 7) << 3;
    *reinterpret_cast<uint4*>(&t[sl][seg]) =
        *reinterpret_cast<const uint4*>(V + ((size_t)(bh * 2048 + s0 + sl) << 6) + seg);
  }
  __syncthreads();
#pragma unroll
  for (int rep = 0; rep < 2; ++rep) {
    int e = tid + rep * 256;
    int hd = e >> 3, ss = (e & 7) << 3;
    u16 tmp[8];
#pragma unroll
    for (int i = 0; i < 8; ++i) tmp[i] = t[ss + i][hd];
    *reinterpret_cast<uint4*>(VT + ((size_t)(bh * 64 + hd) << 11) + s0 + ss) =
        *reinterpret_cast<uint4*>(tmp);
  }
}

// ---------- flash attention over gravity scores ----------
// Scores <= 0, row-max exactly 0 (diagonal) -> no online max tracking.
// Swapped QK^T: S^T = mfma(Zt, Zq) so each lane owns (q=l15, 4 consecutive t),
// enabling ds_write_b64 P writes. P layout [q][t] so PV is unchanged.
// Double-buffered staging: issue next tile's global loads before compute,
// write LDS after compute, one barrier per tile.
__global__ __launch_bounds__(256) void k_attn(const u16* __restrict__ Z,
                                              const float* __restrict__ zsq,
                                              const u16* __restrict__ VT,
                                              const float* __restrict__ gamma,
                                              u16* __restrict__ O) {
  __shared__ u16 Zt[2][64][40];
  __shared__ u16 Vt[2][64][72];
  __shared__ u16 P[64][72];
  __shared__ float tsq[2][64];  // staged as -g2 * zsq[t]

  int tid = threadIdx.x, lane = tid & 63, w = tid >> 6;
  int l15 = lane & 15, lg = lane >> 4;
  int bh = blockIdx.x >> 5, qt = blockIdx.x & 31;
  int q0 = qt << 6;
  int h = bh & 15, b = bh >> 4;
  float gm = gamma[h];
  float g = (gm > 15.f) ? gm : log1pf(__expf(gm));  // softplus
  float g2 = g * 1.4426950408889634f;               // fold log2(e) -> exp2
  float tg2 = 2.f * g2;

  const u16* Zb = Z + ((size_t)bh << 11) * 16;
  const float* zsb = zsq + ((size_t)bh << 11);
  const u16* Vb = VT + ((size_t)bh << 6) * 2048;

  {  // persistent zero K-pad of both Zt buffers (cols 16..31)
    int r = tid >> 2, c4 = (tid & 3) << 2;
    *reinterpret_cast<uint2*>(&Zt[0][r][16 + c4]) = make_uint2(0u, 0u);
    *reinterpret_cast<uint2*>(&Zt[1][r][16 + c4]) = make_uint2(0u, 0u);
  }
  // Q fragment (B operand): col=q=w*16+l15, k=lg*8 (zero for k>=16)
  bf16x8 bq = {};
  if (lg < 2)
    bq = *reinterpret_cast<const bf16x8*>(Zb + (size_t)(q0 + w * 16 + l15) * 16 + lg * 8);
  float gzq = -g2 * zsb[q0 + w * 16 + l15];

  float psum = 0.f;
  f32x4 zero = {0.f, 0.f, 0.f, 0.f};
  f32x4 oacc[4];
#pragma unroll
  for (int ni = 0; ni < 4; ++ni) oacc[ni] = zero;

  // staging registers
  uint2 zt_pre;
  float ts_pre = 0.f;
  uint4 vt_pre0, vt_pre1;
  int zr = tid >> 2, zc4 = (tid & 3) << 2;
  int hd0 = tid >> 3, sg0 = (tid & 7) << 3;
  int hd1 = (tid + 256) >> 3, sg1 = sg0;

#define STAGE_LOAD(T0X)                                                               \
  do {                                                                                \
    zt_pre = *reinterpret_cast<const uint2*>(Zb + (size_t)((T0X) + zr) * 16 + zc4);   \
    if (tid < 64) ts_pre = zsb[(T0X) + tid];                                          \
    vt_pre0 = *reinterpret_cast<const uint4*>(Vb + ((size_t)hd0 << 11) + (T0X) + sg0);\
    vt_pre1 = *reinterpret_cast<const uint4*>(Vb + ((size_t)hd1 << 11) + (T0X) + sg1);\
  } while (0)

#define STAGE_WRITE(BUFX)                                                  \
  do {                                                                     \
    *reinterpret_cast<uint2*>(&Zt[(BUFX)][zr][zc4]) = zt_pre;              \
    if (tid < 64) tsq[(BUFX)][tid] = -g2 * ts_pre;                         \
    *reinterpret_cast<uint4*>(&Vt[(BUFX)][hd0][sg0]) = vt_pre0;            \
    *reinterpret_cast<uint4*>(&Vt[(BUFX)][hd1][sg1]) = vt_pre1;            \
  } while (0)

  STAGE_LOAD(0);
  STAGE_WRITE(0);
  __syncthreads();

  for (int tt = 0; tt < 32; ++tt) {
    int buf = tt & 1;
    if (tt < 31) STAGE_LOAD((tt + 1) << 6);

    // S^T tile: A = Zt rows (t), B = Zq (q). D: col=l15=q, row=lg*4+j=t.
    bf16x8 bt[4];
#pragma unroll
    for (int ni = 0; ni < 4; ++ni)
      bt[ni] = *reinterpret_cast<const bf16x8*>(&Zt[buf][ni * 16 + l15][lg * 8]);
    f32x4 scT[4];
#pragma unroll
    for (int ni = 0; ni < 4; ++ni) scT[ni] = MFMA16(bt[ni], bq, zero);

#pragma unroll
    for (int ni = 0; ni < 4; ++ni) {
      f32x4 tq = *reinterpret_cast<const f32x4*>(&tsq[buf][ni * 16 + lg * 4]);  // -g2*tsq, broadcast
      u16 pk[4];
#pragma unroll
      for (int j = 0; j < 4; ++j) {
        float e = fmaf(tg2, scT[ni][j], gzq + tq[j]);
        e = fminf(e, 0.f);
        float p = exp2f(e);
        psum += p;
        pk[j] = f2b(p);
      }
      *reinterpret_cast<uint2*>(&P[w * 16 + l15][ni * 16 + lg * 4]) =
          *reinterpret_cast<uint2*>(pk);
    }

    // PV: oacc += P * Vt   (same-wave P write->read, LDS in-order)
#pragma unroll
    for (int ks = 0; ks < 2; ++ks) {
      bf16x8 pa = *reinterpret_cast<const bf16x8*>(&P[w * 16 + l15][ks * 32 + lg * 8]);
#pragma unroll
      for (int ni = 0; ni < 4; ++ni) {
        bf16x8 vb = *reinterpret_cast<const bf16x8*>(&Vt[buf][ni * 16 + l15][ks * 32 + lg * 8]);
        oacc[ni] = MFMA16(pa, vb, oacc[ni]);
      }
    }

    if (tt < 31) {
      STAGE_WRITE(buf ^ 1);
      __syncthreads();
    }
  }
#undef STAGE_LOAD
#undef STAGE_WRITE

  // row sums: lane holds partial for q = w*16+l15; reduce across lg groups
  psum += __shfl_xor(psum, 16, 64);
  psum += __shfl_xor(psum, 32, 64);

#pragma unroll
  for (int j = 0; j < 4; ++j) {
    float rs = __shfl(psum, lg * 4 + j, 16);  // rowsum for q = w*16+lg*4+j
    float inv = 1.f / rs;
    int s = q0 + w * 16 + lg * 4 + j;
    u16* orow = O + ((size_t)(b * 2048 + s) << 10) + h * 64;
#pragma unroll
    for (int ni = 0; ni < 4; ++ni) orow[ni * 16 + l15] = f2b(oacc[ni][j] * inv);
  }
}

// ---------- updated_coords = coords @ Wn + bn (fp32) ----------
__global__ void k_coords(const float* __restrict__ C, const float* __restrict__ Wn,
                         const float* __restrict__ bn, float* __restrict__ out) {
  int gid = blockIdx.x * 256 + threadIdx.x;  // 262144
  int bs = gid >> 6, c = gid & 63;
  const float* crow = C + (size_t)bs * 64;
  float acc = bn[c];
#pragma unroll 8
  for (int k = 0; k < 64; ++k) acc = fmaf(crow[k], Wn[k * 64 + c], acc);
  out[gid] = acc;
}

extern "C" void kernel_launch(void* const* d_in, const int* in_sizes, int n_in,
                              void* d_out, int out_size, void* d_ws, size_t ws_size,
                              hipStream_t stream) {
  const float* hs     = (const float*)d_in[0];
  const float* coords = (const float*)d_in[1];
  const float* Wv     = (const float*)d_in[2];
  const float* bv     = (const float*)d_in[3];
  const float* Wc     = (const float*)d_in[4];
  const float* bc     = (const float*)d_in[5];
  const float* Wn     = (const float*)d_in[6];
  const float* bn     = (const float*)d_in[7];
  const float* Wo     = (const float*)d_in[8];
  const float* bo     = (const float*)d_in[9];
  const float* gamma  = (const float*)d_in[10];
  float* out_h = (float*)d_out;
  float* out_c = out_h + 4194304;

  char* ws = (char*)d_ws;
  u16*   HSb  = (u16*)(ws + 0);          // 8 MB   (reused as O after gemm1)
  u16*   O    = (u16*)(ws + 0);
  u16*   WvT  = (u16*)(ws + 8388608);    // 2 MB
  u16*   WoT  = (u16*)(ws + 10485760);   // 2 MB
  u16*   Zw   = (u16*)(ws + 12582912);   // 2 MB
  float* zsqw = (float*)(ws + 14680064); // 0.25 MB
  u16*   Vw   = (u16*)(ws + 14942208);   // 8 MB
  u16*   VTw  = (u16*)(ws + 23330816);   // 8 MB  -> total 31.7 MB

  k_cvt<<<4096, 256, 0, stream>>>(hs, HSb, 4194304);
  k_wT<<<256, 256, 0, stream>>>(Wv, WvT);
  k_wT<<<256, 256, 0, stream>>>(Wo, WoT);
  k_z<<<256, 256, 0, stream>>>(coords, Wc, bc, Zw, zsqw);
  k_gemm<1><<<512, 256, 0, stream>>>(HSb, WvT, bv, Vw, 4096, 1024, 1024);
  k_vT<<<1024, 256, 0, stream>>>(Vw, VTw);
  k_attn<<<1024, 256, 0, stream>>>(Zw, zsqw, VTw, gamma, O);
  k_gemm<0><<<512, 256, 0, stream>>>(O, WoT, bo, out_h, 4096, 1024, 1024);
  k_coords<<<1024, 256, 0, stream>>>(coords, Wn, bn, out_c);
}